// Round 1
// baseline (193.731 us; speedup 1.0000x reference)
//
#include <hip/hip_runtime.h>

// Fused Stream_PreNet: conv1 (1x7, 8->96) + conv2 (7x1, 96->96), symmetric pad,
// bf16 MFMA (16x16x32), fp32 accumulate. Intermediate out1 tile lives in LDS only.
//
// d_ws usage: w1t (96*64 bf16) + w2t (96*672 bf16) = 141,312 bytes.

#define B_   8
#define H_   512
#define W_   256
#define CIN  8
#define COUT 96
#define TH   8            // output rows per block
#define TW   16           // output cols per block
#define ROWS (TH + 6)     // 14 out1 rows (halo for 7x1)
#define XC   (TW + 6)     // 22 x cols (halo for 1x7)
#define PADC 104          // o1 inner dim pad: 208B stride, 16B aligned, ~2-way banks
#define NTHREADS 384      // 6 waves; wave w owns channel tile [16w,16w+16)

typedef __bf16 bf16x8 __attribute__((ext_vector_type(8)));
typedef float  f32x4  __attribute__((ext_vector_type(4)));
typedef int    i32x4  __attribute__((ext_vector_type(4)));

__device__ __forceinline__ unsigned short f2bf(float f) {
  unsigned u = __builtin_bit_cast(unsigned, f);
  u += 0x7FFFu + ((u >> 16) & 1u);   // RNE
  return (unsigned short)(u >> 16);
}

__device__ __forceinline__ bf16x8 ld16s(const unsigned short* p) {
  i32x4 t = *(const i32x4*)p;        // 16B-aligned -> ds_read_b128 / dwordx4
  return __builtin_bit_cast(bf16x8, t);
}

__device__ __forceinline__ f32x4 mfma16(bf16x8 a, bf16x8 b, f32x4 c) {
  return __builtin_amdgcn_mfma_f32_16x16x32_bf16(a, b, c, 0, 0, 0);
}

// jnp.pad mode='symmetric': -1->0, -2->1, -3->2 ; N->N-1, N+1->N-2, ...
__device__ __forceinline__ int symH(int i) { return i < 0 ? -1 - i : (i >= H_ ? 2 * H_ - 1 - i : i); }
__device__ __forceinline__ int symW(int i) { return i < 0 ? -1 - i : (i >= W_ ? 2 * W_ - 1 - i : i); }

// ---- weight prep: transpose + cast to bf16 ----
// w1t[n][kc8], kc8 = k*8+c, zero-padded 56..63.  w2t[n][kc], kc = k*96+c.
__global__ void prep_kernel(const float* __restrict__ W1, const float* __restrict__ W2,
                            unsigned short* __restrict__ w1t, unsigned short* __restrict__ w2t) {
  int i = blockIdx.x * 256 + threadIdx.x;
  if (i < 96 * 64) {
    int n = i >> 6, kc = i & 63;
    float v = (kc < 56) ? W1[kc * 96 + n] : 0.f;   // W1 flat [(k*8+c)*96 + n]
    w1t[i] = f2bf(v);                              // i == n*64 + kc
  }
  if (i < 96 * 672) {
    int n = i / 672, kc = i - n * 672;
    w2t[i] = f2bf(W2[kc * 96 + n]);                // W2 flat [(k*96+c)*96 + n]
  }
}

__global__ __launch_bounds__(NTHREADS, 3)
void conv_main(const float* __restrict__ x, const float* __restrict__ b1,
               const float* __restrict__ b2, const unsigned short* __restrict__ w1t,
               const unsigned short* __restrict__ w2t, float* __restrict__ out) {
  __shared__ __align__(16) unsigned short o1[ROWS][TW][PADC];  // 46,592 B
  __shared__ __align__(16) unsigned short xt[ROWS][XC][CIN];   //  4,928 B

  const int tid = threadIdx.x;
  const int w0  = blockIdx.x * TW;
  const int h0  = blockIdx.y * TH;
  const int b   = blockIdx.z;

  // ---- stage x halo tile (symmetric pad applied here), fp32 -> bf16 ----
  const float* xb = x + (size_t)b * H_ * W_ * CIN;
  for (int idx = tid; idx < ROWS * XC; idx += NTHREADS) {
    int rr = idx / XC, cc = idx - rr * XC;
    int hr = symH(h0 - 3 + rr);
    int wc = symW(w0 - 3 + cc);
    const float4* px = (const float4*)(xb + ((size_t)hr * W_ + wc) * CIN);
    float4 v0 = px[0], v1 = px[1];
    unsigned p0 = ((unsigned)f2bf(v0.y) << 16) | f2bf(v0.x);
    unsigned p1 = ((unsigned)f2bf(v0.w) << 16) | f2bf(v0.z);
    unsigned p2 = ((unsigned)f2bf(v1.y) << 16) | f2bf(v1.x);
    unsigned p3 = ((unsigned)f2bf(v1.w) << 16) | f2bf(v1.z);
    *(i32x4*)&xt[rr][cc][0] = (i32x4){(int)p0, (int)p1, (int)p2, (int)p3};
  }

  const int wid  = tid >> 6;        // 0..5 = channel N-tile
  const int lane = tid & 63;
  const int l15  = lane & 15;       // A: m-row / B: n-col / D: n-col
  const int g    = lane >> 4;       // 0..3: k-group / D row group
  const int cf   = wid * 16 + l15;  // output channel

  // conv1 B fragments: B[k8][n] from w1t[n][k8]; slice0 k=g, slice1 k=4+g (g==3 -> zero pad)
  bf16x8 b1f0 = ld16s(&w1t[cf * 64 + 8 * g]);
  bf16x8 b1f1 = ld16s(&w1t[cf * 64 + 32 + 8 * g]);
  float bias1 = b1[cf];
  const i32x4 z4 = {0, 0, 0, 0};

  __syncthreads();

  // ---- conv1: out1 rows 0..13 (row rr = image row symH(h0-3+rr)) ----
  for (int rr = 0; rr < ROWS; ++rr) {
    // A[m=p][k8=32s+8g+j] = xt[rr][p + k][c=j], k = 4s+g
    bf16x8 a0 = ld16s(&xt[rr][l15 + g][0]);
    bf16x8 a1 = (g < 3) ? ld16s(&xt[rr][l15 + 4 + g][0]) : __builtin_bit_cast(bf16x8, z4);
    f32x4 acc = {0.f, 0.f, 0.f, 0.f};
    acc = mfma16(a0, b1f0, acc);
    acc = mfma16(a1, b1f1, acc);
    // D[m=4g+r][n=l15] -> o1[rr][pixel][channel]
#pragma unroll
    for (int r = 0; r < 4; ++r)
      o1[rr][g * 4 + r][cf] = f2bf(acc[r] + bias1);
  }

  // conv2 B fragments: 21 K-slices of w2t column block [cf][*] (84 VGPRs)
  bf16x8 b2f[21];
#pragma unroll
  for (int sb = 0; sb < 21; ++sb)
    b2f[sb] = ld16s(&w2t[cf * 672 + 32 * sb + 8 * g]);
  float bias2 = b2[cf];

  __syncthreads();

  // ---- conv2: for each out1 row, its 3 A-frags feed all valid taps k ----
  f32x4 acc[TH];
#pragma unroll
  for (int m = 0; m < TH; ++m) acc[m] = (f32x4){0.f, 0.f, 0.f, 0.f};

#pragma unroll
  for (int rr = 0; rr < ROWS; ++rr) {
    // A[m=p][c = 32s+8g+j] = o1[rr][p][c]
    bf16x8 a0 = ld16s(&o1[rr][l15][8 * g]);
    bf16x8 a1 = ld16s(&o1[rr][l15][32 + 8 * g]);
    bf16x8 a2 = ld16s(&o1[rr][l15][64 + 8 * g]);
#pragma unroll
    for (int k = 0; k < 7; ++k) {
      int m = rr - k;                 // output row index in tile
      if (m < 0 || m >= TH) continue; // folds to constants after unroll
      acc[m] = mfma16(a0, b2f[3 * k + 0], acc[m]);
      acc[m] = mfma16(a1, b2f[3 * k + 1], acc[m]);
      acc[m] = mfma16(a2, b2f[3 * k + 2], acc[m]);
    }
  }

  // ---- epilogue: out[b][h0+m][w0+4g+r][cf] = acc[m][r] + b2 ----
  const size_t obase = (((size_t)b * H_ + h0) * W_ + (w0 + g * 4)) * COUT + cf;
#pragma unroll
  for (int m = 0; m < TH; ++m) {
#pragma unroll
    for (int r = 0; r < 4; ++r)
      out[obase + (size_t)m * (W_ * COUT) + (size_t)r * COUT] = acc[m][r] + bias2;
  }
}

extern "C" void kernel_launch(void* const* d_in, const int* in_sizes, int n_in,
                              void* d_out, int out_size, void* d_ws, size_t ws_size,
                              hipStream_t stream) {
  const float* x  = (const float*)d_in[0];
  const float* W1 = (const float*)d_in[1];
  const float* b1 = (const float*)d_in[2];
  const float* W2 = (const float*)d_in[3];
  const float* b2 = (const float*)d_in[4];
  // d_in[5] = training (unused)

  unsigned short* w1t = (unsigned short*)d_ws;   // 96*64 bf16
  unsigned short* w2t = w1t + 96 * 64;           // 96*672 bf16  (total 141,312 B)
  float* out = (float*)d_out;

  prep_kernel<<<dim3(252), dim3(256), 0, stream>>>(W1, W2, w1t, w2t);
  conv_main<<<dim3(W_ / TW, H_ / TH, B_), dim3(NTHREADS), 0, stream>>>(
      x, b1, b2, w1t, w2t, out);
}